// Round 3
// baseline (491.625 us; speedup 1.0000x reference)
//
#include <hip/hip_runtime.h>
#include <hip/hip_bf16.h>
#include <cstdint>

#define DIM 1536
#define NHEADS 12
#define HD 128
#define SEQ 3840

typedef float f32x4 __attribute__((ext_vector_type(4)));
typedef __bf16 bf16x8 __attribute__((ext_vector_type(8)));
typedef __bf16 bf16x4 __attribute__((ext_vector_type(4)));
typedef __bf16 bf16x2 __attribute__((ext_vector_type(2)));
typedef unsigned int u32;
typedef u32 u32x4 __attribute__((ext_vector_type(4)));

#define GLLD(g, l) __builtin_amdgcn_global_load_lds( \
    (const __attribute__((address_space(1))) void*)(g), \
    (__attribute__((address_space(3))) void*)(l), 16, 0, 0)

// ---------------- fp32 -> bf16 convert ----------------
__global__ __launch_bounds__(256) void cvt_bf16(const float* __restrict__ in,
                                                __bf16* __restrict__ out, int n4) {
    int i = blockIdx.x * 256 + threadIdx.x;
    if (i < n4) {
        f32x4 v = ((const f32x4*)in)[i];
        bf16x4 o;
        o[0] = (__bf16)v[0]; o[1] = (__bf16)v[1];
        o[2] = (__bf16)v[2]; o[3] = (__bf16)v[3];
        ((bf16x4*)out)[i] = o;
    }
}

// ---------------- GEMM: C[M][N] = A[M][K] * B[N][K]^T + bias ----------------
// 128x128 tile, BK=32, 4 waves (2x2), global_load_lds(16B) staging (m97 pattern).
template <int OUTF32>
__global__ __launch_bounds__(256) void gemm_bt(
    const __bf16* __restrict__ A,
    const __bf16* __restrict__ B0, const __bf16* __restrict__ B1, const __bf16* __restrict__ B2,
    const float* __restrict__ bias0, const float* __restrict__ bias1, const float* __restrict__ bias2,
    void* __restrict__ C0v, void* __restrict__ C1v, void* __restrict__ C2v,
    int N, int K) {
    const __bf16* B = B0; const float* bias = bias0; void* Cv = C0v;
    if (blockIdx.z == 1) { B = B1; bias = bias1; Cv = C1v; }
    else if (blockIdx.z == 2) { B = B2; bias = bias2; Cv = C2v; }

    __shared__ __bf16 As[128 * 32];
    __shared__ __bf16 Bs[128 * 32];

    const int t = threadIdx.x;
    const int w = t >> 6;
    const int lane = t & 63;
    const int lr = lane & 15, lg = lane >> 4;
    const int wr = (w >> 1) * 64, wc = (w & 1) * 64;
    const int wb = w * 512;   // wave's linear LDS slice (elements): 64 lanes x 16B

    const long long rowA = (long long)blockIdx.y * 128 + (t >> 2);
    const long long rowB = (long long)blockIdx.x * 128 + (t >> 2);
    const int kcol = (t & 3) * 8;

    const __bf16* pa0 = A + rowA * K + kcol;
    const __bf16* pa1 = pa0 + 64LL * K;
    const __bf16* pb0 = B + rowB * K + kcol;
    const __bf16* pb1 = pb0 + 64LL * K;

    f32x4 acc[4][4] = {};

#pragma unroll 1
    for (int kk = 0; kk < K; kk += 32) {
        __syncthreads();                 // prev step's LDS reads complete
        GLLD(pa0 + kk, As + wb);
        GLLD(pa1 + kk, As + 2048 + wb);
        GLLD(pb0 + kk, Bs + wb);
        GLLD(pb1 + kk, Bs + 2048 + wb);
        __syncthreads();                 // drains vmcnt -> tile ready
        bf16x8 af[4], bfr[4];
#pragma unroll
        for (int m = 0; m < 4; m++)
            af[m] = *(const bf16x8*)(As + (wr + m * 16 + lr) * 32 + lg * 8);
#pragma unroll
        for (int n = 0; n < 4; n++)
            bfr[n] = *(const bf16x8*)(Bs + (wc + n * 16 + lr) * 32 + lg * 8);
#pragma unroll
        for (int m = 0; m < 4; m++)
#pragma unroll
            for (int n = 0; n < 4; n++)
                acc[m][n] = __builtin_amdgcn_mfma_f32_16x16x32_bf16(af[m], bfr[n], acc[m][n], 0, 0, 0);
    }

    const int cb = blockIdx.x * 128 + wc;
    const int rb_ = blockIdx.y * 128 + wr;
#pragma unroll
    for (int n = 0; n < 4; n++) {
        int col = cb + n * 16 + lr;
        float bv = bias[col];
#pragma unroll
        for (int m = 0; m < 4; m++) {
            int row0 = rb_ + m * 16 + lg * 4;
#pragma unroll
            for (int r = 0; r < 4; r++) {
                float v = acc[m][n][r] + bv;
                if (OUTF32) ((float*)Cv)[(long long)(row0 + r) * N + col] = v;
                else ((__bf16*)Cv)[(long long)(row0 + r) * N + col] = (__bf16)v;
            }
        }
    }
}

// ---------------- RMSNorm + RoPE, write [NH][SEQ][HD] ----------------
__global__ __launch_bounds__(256) void norm_rope(
    const __bf16* __restrict__ pre,   // [SEQ][DIM]
    const float* __restrict__ gvec,   // [DIM]
    const float* __restrict__ fcos,   // [1024][64]
    const float* __restrict__ fsin,
    __bf16* __restrict__ out) {       // [NH][SEQ][HD]
    const int s = blockIdx.x;
    const int t = threadIdx.x;
    float a[3], b[3];
    float ss = 0.f;
#pragma unroll
    for (int j = 0; j < 3; j++) {
        int p = t + 256 * j;
        bf16x2 v = *(const bf16x2*)(pre + (size_t)s * DIM + 2 * p);
        a[j] = (float)v[0]; b[j] = (float)v[1];
        ss += a[j] * a[j] + b[j] * b[j];
    }
    for (int off = 32; off; off >>= 1) ss += __shfl_down(ss, off);
    __shared__ float red[4];
    if ((t & 63) == 0) red[t >> 6] = ss;
    __syncthreads();
    float mean = (red[0] + red[1] + red[2] + red[3]) * (1.f / DIM);
    float rms = rsqrtf(mean + 1e-6f);
    const int fi = s / 640, hi2 = (s % 640) >> 5, wi = s & 31;
#pragma unroll
    for (int j = 0; j < 3; j++) {
        int p = t + 256 * j;
        int c = p & 63;
        int pos = (c < 22) ? fi : ((c < 43) ? hi2 : wi);
        float fc = fcos[pos * 64 + c];
        float fs = fsin[pos * 64 + c];
        float av = a[j] * rms * gvec[2 * p];
        float bv = b[j] * rms * gvec[2 * p + 1];
        float orr = av * fc - bv * fs;
        float oi = av * fs + bv * fc;
        int hh = p >> 6;
        bf16x2 o; o[0] = (__bf16)orr; o[1] = (__bf16)oi;
        *(bf16x2*)(out + ((size_t)hh * SEQ + s) * HD + 2 * c) = o;
    }
}

// ---------------- transpose [SEQ][DIM] -> [DIM][SEQ] with kv-slot permute ----
__global__ __launch_bounds__(256) void transpose_bf16(
    const __bf16* __restrict__ in, __bf16* __restrict__ out) {
    __shared__ __bf16 tile[64][68];
    const int t = threadIdx.x;
    const int sb = blockIdx.x * 64, cb = blockIdx.y * 64;
    const int tx = t & 15, ty = t >> 4;
#pragma unroll
    for (int i = 0; i < 4; i++) {
        int r = ty + i * 16;
        bf16x4 v = *(const bf16x4*)(in + (size_t)(sb + r) * DIM + cb + tx * 4);
        *(bf16x4*)&tile[r][tx * 4] = v;
    }
    __syncthreads();
    int s0 = sb + tx * 4;
    int j = (s0 >> 2) & 7;
    int u = (j < 4) ? (j << 1) : ((j << 1) - 7);
    int sp = (s0 & ~31) + (u << 2);
#pragma unroll
    for (int i = 0; i < 4; i++) {
        int c = ty + i * 16;
        bf16x4 v;
        v[0] = tile[tx * 4 + 0][c]; v[1] = tile[tx * 4 + 1][c];
        v[2] = tile[tx * 4 + 2][c]; v[3] = tile[tx * 4 + 3][c];
        *(bf16x4*)(out + (size_t)(cb + c) * SEQ + sp) = v;
    }
}

// ---------------- flash attention ----------------
// 1D grid of 1440 one-wave blocks; 32 q-rows/wave.
// XCD-partitioned task map: XCD j (= bid%8) owns contiguous tasks [180j,180j+180)
// so its resident waves touch ~2 heads (~3.8MB K/V) -> per-XCD-L2 resident.
__global__ __launch_bounds__(64) void attn(
    const __bf16* __restrict__ Q,    // [NH][SEQ][HD]
    const __bf16* __restrict__ Kk,   // [NH][SEQ][HD]
    const __bf16* __restrict__ Vp,   // [NH][HD][SEQ] (kv-permuted in 32-blocks)
    __bf16* __restrict__ O) {        // [SEQ][DIM]
    const int bid = blockIdx.x;
    const int task = (bid & 7) * 180 + (bid >> 3);
    const int h = task / 120;
    const int qb = task - h * 120;
    const int q0 = qb * 32;
    const int lane = threadIdx.x;
    const int lq = lane & 15, g = lane >> 4;

    const __bf16* Qh = Q + (size_t)h * SEQ * HD;
    const __bf16* Kh = Kk + (size_t)h * SEQ * HD;
    const __bf16* Vh = Vp + (size_t)h * HD * SEQ;

    bf16x8 qf[2][4];
#pragma unroll
    for (int qg = 0; qg < 2; qg++)
#pragma unroll
        for (int c = 0; c < 4; c++)
            qf[qg][c] = *(const bf16x8*)(Qh + (size_t)(q0 + qg * 16 + lq) * HD + c * 32 + g * 8);

    f32x4 acc[8][2] = {};
    float m[2] = {-1e30f, -1e30f}, l[2] = {0.f, 0.f};
    const float SCL2 = 0.1275365308119098f;   // (1/sqrt(128)) * log2(e)
    const float THR_RAW = 90.50966799187809f; // 8 nats / (1/sqrt(128))

    // K fragments for kv=0 preloaded; inside the loop we prefetch kv+32.
    const __bf16* kbase = Kh + (size_t)lq * HD + g * 8;
    bf16x8 kcur[2][4];
#pragma unroll
    for (int kvg = 0; kvg < 2; kvg++)
#pragma unroll
        for (int c = 0; c < 4; c++)
            kcur[kvg][c] = *(const bf16x8*)(kbase + (size_t)(kvg * 16) * HD + c * 32);

#pragma unroll 2
    for (int kv = 0; kv < SEQ; kv += 32) {
        // V for this step: consumed last (after softmax) -> latency self-hiding
        bf16x8 vf[8];
#pragma unroll
        for (int dt = 0; dt < 8; dt++)
            vf[dt] = *(const bf16x8*)(Vh + (size_t)(dt * 16 + lq) * SEQ + kv + g * 8);

        // prefetch next K tile (dummy re-read of tile 0 on last iter)
        const int kn = (kv + 32 < SEQ) ? kv + 32 : 0;
        bf16x8 knx[2][4];
#pragma unroll
        for (int kvg = 0; kvg < 2; kvg++)
#pragma unroll
            for (int c = 0; c < 4; c++)
                knx[kvg][c] = *(const bf16x8*)(kbase + (size_t)(kn + kvg * 16) * HD + c * 32);

        f32x4 sc[2][2] = {};
#pragma unroll
        for (int c = 0; c < 4; c++)
#pragma unroll
            for (int kvg = 0; kvg < 2; kvg++)
#pragma unroll
                for (int qg = 0; qg < 2; qg++)
                    sc[kvg][qg] = __builtin_amdgcn_mfma_f32_16x16x32_bf16(kcur[kvg][c], qf[qg][c], sc[kvg][qg], 0, 0, 0);

        bf16x8 pa[2];
#pragma unroll
        for (int qg = 0; qg < 2; qg++) {
            float pm = fmaxf(fmaxf(fmaxf(sc[0][qg][0], sc[0][qg][1]), fmaxf(sc[0][qg][2], sc[0][qg][3])),
                             fmaxf(fmaxf(sc[1][qg][0], sc[1][qg][1]), fmaxf(sc[1][qg][2], sc[1][qg][3])));
            pm = fmaxf(pm, __shfl_xor(pm, 16));
            pm = fmaxf(pm, __shfl_xor(pm, 32));
            if (!__all(pm <= m[qg] + THR_RAW)) {   // defer-max
                float mn = fmaxf(m[qg], pm);
                float al = __builtin_amdgcn_exp2f(SCL2 * (m[qg] - mn));
                m[qg] = mn;
                l[qg] *= al;
#pragma unroll
                for (int dt = 0; dt < 8; dt++)
#pragma unroll
                    for (int r = 0; r < 4; r++) acc[dt][qg][r] *= al;
            }
            float ms = SCL2 * m[qg];
            float p[8], ls = 0.f;
#pragma unroll
            for (int r = 0; r < 4; r++) { p[r] = __builtin_amdgcn_exp2f(SCL2 * sc[0][qg][r] - ms); ls += p[r]; }
#pragma unroll
            for (int r = 0; r < 4; r++) { p[4 + r] = __builtin_amdgcn_exp2f(SCL2 * sc[1][qg][r] - ms); ls += p[4 + r]; }
            ls += __shfl_xor(ls, 16);
            ls += __shfl_xor(ls, 32);
            l[qg] += ls;
#pragma unroll
            for (int i = 0; i < 8; i++) pa[qg][i] = (__bf16)p[i];
        }

#pragma unroll
        for (int dt = 0; dt < 8; dt++)
#pragma unroll
            for (int qg = 0; qg < 2; qg++)
                acc[dt][qg] = __builtin_amdgcn_mfma_f32_16x16x32_bf16(vf[dt], pa[qg], acc[dt][qg], 0, 0, 0);

        // advance prefetched K
#pragma unroll
        for (int kvg = 0; kvg < 2; kvg++)
#pragma unroll
            for (int c = 0; c < 4; c++)
                kcur[kvg][c] = knx[kvg][c];
    }

#pragma unroll
    for (int qg = 0; qg < 2; qg++) {
        float inv = 1.f / l[qg];
#pragma unroll
        for (int dt = 0; dt < 8; dt++) {
            bf16x4 o;
#pragma unroll
            for (int r = 0; r < 4; r++) o[r] = (__bf16)(acc[dt][qg][r] * inv);
            *(bf16x4*)(O + (size_t)(q0 + qg * 16 + lq) * DIM + h * HD + dt * 16 + g * 4) = o;
        }
    }
}

extern "C" void kernel_launch(void* const* d_in, const int* in_sizes, int n_in,
                              void* d_out, int out_size, void* d_ws, size_t ws_size,
                              hipStream_t stream) {
    const float* x = (const float*)d_in[0];
    const float* Wq = (const float*)d_in[1];
    const float* bq = (const float*)d_in[2];
    const float* Wk = (const float*)d_in[3];
    const float* bk = (const float*)d_in[4];
    const float* Wv = (const float*)d_in[5];
    const float* bv = (const float*)d_in[6];
    const float* Wo = (const float*)d_in[7];
    const float* bo = (const float*)d_in[8];
    const float* gq = (const float*)d_in[9];
    const float* gk = (const float*)d_in[10];
    const float* fcos = (const float*)d_in[11];
    const float* fsin = (const float*)d_in[12];
    float* out = (float*)d_out;

    char* ws = (char*)d_ws;
    const size_t SZ_SD = (size_t)SEQ * DIM * 2;   // 11.25 MB
    const size_t SZ_W = (size_t)DIM * DIM * 2;    // 4.5 MB
    __bf16* xb   = (__bf16*)ws;            ws += SZ_SD;   // also reused as Qb
    __bf16* Wqb  = (__bf16*)ws;            ws += SZ_W;
    __bf16* Wkb  = (__bf16*)ws;            ws += SZ_W;
    __bf16* Wvb  = (__bf16*)ws;            ws += SZ_W;
    __bf16* Wob  = (__bf16*)ws;            ws += SZ_W;
    __bf16* qpre = (__bf16*)ws;            ws += SZ_SD;   // also reused as ob
    __bf16* kpre = (__bf16*)ws;            ws += SZ_SD;
    __bf16* vpre = (__bf16*)ws;            ws += SZ_SD;
    __bf16* Kb   = (__bf16*)ws;            ws += SZ_SD;
    __bf16* Vtb  = (__bf16*)ws;            ws += SZ_SD;
    __bf16* Qb = xb;     // xb dead after QKV GEMM
    __bf16* ob = qpre;   // qpre dead after norm_rope(q)

    int n4 = SEQ * DIM / 4;
    cvt_bf16<<<(n4 + 255) / 256, 256, 0, stream>>>(x, xb, n4);
    n4 = DIM * DIM / 4;
    cvt_bf16<<<(n4 + 255) / 256, 256, 0, stream>>>(Wq, Wqb, n4);
    cvt_bf16<<<(n4 + 255) / 256, 256, 0, stream>>>(Wk, Wkb, n4);
    cvt_bf16<<<(n4 + 255) / 256, 256, 0, stream>>>(Wv, Wvb, n4);
    cvt_bf16<<<(n4 + 255) / 256, 256, 0, stream>>>(Wo, Wob, n4);

    gemm_bt<0><<<dim3(DIM / 128, SEQ / 128, 3), 256, 0, stream>>>(
        xb, Wqb, Wkb, Wvb, bq, bk, bv, qpre, kpre, vpre, DIM, DIM);

    norm_rope<<<SEQ, 256, 0, stream>>>(qpre, gq, fcos, fsin, Qb);
    norm_rope<<<SEQ, 256, 0, stream>>>(kpre, gk, fcos, fsin, Kb);
    transpose_bf16<<<dim3(SEQ / 64, DIM / 64), 256, 0, stream>>>(vpre, Vtb);

    attn<<<dim3(NHEADS * (SEQ / 32)), 64, 0, stream>>>(Qb, Kb, Vtb, ob);

    gemm_bt<1><<<dim3(DIM / 128, SEQ / 128, 1), 256, 0, stream>>>(
        ob, Wob, Wob, Wob, bo, bo, bo, out, out, out, DIM, DIM);
}

// Round 4
// 335.999 us; speedup vs baseline: 1.4632x; 1.4632x over previous
//
#include <hip/hip_runtime.h>
#include <hip/hip_bf16.h>
#include <cstdint>

#define DIM 1536
#define NHEADS 12
#define HD 128
#define SEQ 3840

typedef float f32x4 __attribute__((ext_vector_type(4)));
typedef __bf16 bf16x8 __attribute__((ext_vector_type(8)));
typedef __bf16 bf16x4 __attribute__((ext_vector_type(4)));
typedef __bf16 bf16x2 __attribute__((ext_vector_type(2)));
typedef unsigned int u32;
typedef u32 u32x4 __attribute__((ext_vector_type(4)));

#define GLLD(g, l) __builtin_amdgcn_global_load_lds( \
    (const __attribute__((address_space(1))) void*)(g), \
    (__attribute__((address_space(3))) void*)(l), 16, 0, 0)

// ---------------- fp32 -> bf16 convert ----------------
__global__ __launch_bounds__(256) void cvt_bf16(const float* __restrict__ in,
                                                __bf16* __restrict__ out, int n4) {
    int i = blockIdx.x * 256 + threadIdx.x;
    if (i < n4) {
        f32x4 v = ((const f32x4*)in)[i];
        bf16x4 o;
        o[0] = (__bf16)v[0]; o[1] = (__bf16)v[1];
        o[2] = (__bf16)v[2]; o[3] = (__bf16)v[3];
        ((bf16x4*)out)[i] = o;
    }
}

// ---------------- GEMM: C[M][N] = A[M][K] * B[N][K]^T + bias ----------------
// 128x128 tile, BK=32, 4 waves (2x2); double-buffered global_load_lds staging:
// stage(k+1) issued before compute(k) -> loads in flight under the MFMAs,
// drained only by the single per-step barrier.
template <int OUTF32>
__global__ __launch_bounds__(256) void gemm_bt(
    const __bf16* __restrict__ A,
    const __bf16* __restrict__ B0, const __bf16* __restrict__ B1, const __bf16* __restrict__ B2,
    const float* __restrict__ bias0, const float* __restrict__ bias1, const float* __restrict__ bias2,
    void* __restrict__ C0v, void* __restrict__ C1v, void* __restrict__ C2v,
    int N, int K) {
    const __bf16* B = B0; const float* bias = bias0; void* Cv = C0v;
    if (blockIdx.z == 1) { B = B1; bias = bias1; Cv = C1v; }
    else if (blockIdx.z == 2) { B = B2; bias = bias2; Cv = C2v; }

    __shared__ __bf16 As[2][128 * 32];
    __shared__ __bf16 Bs[2][128 * 32];

    const int t = threadIdx.x;
    const int w = t >> 6;
    const int lane = t & 63;
    const int lr = lane & 15, lg = lane >> 4;
    const int wr = (w >> 1) * 64, wc = (w & 1) * 64;
    const int wb = w * 512;   // wave's linear LDS slice (elements)

    const long long rowA = (long long)blockIdx.y * 128 + (t >> 2);
    const long long rowB = (long long)blockIdx.x * 128 + (t >> 2);
    const int kcol = (t & 3) * 8;

    const __bf16* pa0 = A + rowA * K + kcol;
    const __bf16* pa1 = pa0 + 64LL * K;
    const __bf16* pb0 = B + rowB * K + kcol;
    const __bf16* pb1 = pb0 + 64LL * K;

    f32x4 acc[4][4] = {};

    // stage K-step kk into buffer b
    auto stage = [&](int kk, int b) {
        GLLD(pa0 + kk, &As[b][wb]);
        GLLD(pa1 + kk, &As[b][2048 + wb]);
        GLLD(pb0 + kk, &Bs[b][wb]);
        GLLD(pb1 + kk, &Bs[b][2048 + wb]);
    };

    stage(0, 0);
    int buf = 0;
#pragma unroll 1
    for (int kk = 0; kk < K; kk += 32) {
        __syncthreads();                 // drains stage(kk); gates prev reads vs next overwrite
        if (kk + 32 < K) stage(kk + 32, buf ^ 1);
        bf16x8 af[4], bfr[4];
#pragma unroll
        for (int m = 0; m < 4; m++)
            af[m] = *(const bf16x8*)(&As[buf][(wr + m * 16 + lr) * 32 + lg * 8]);
#pragma unroll
        for (int n = 0; n < 4; n++)
            bfr[n] = *(const bf16x8*)(&Bs[buf][(wc + n * 16 + lr) * 32 + lg * 8]);
#pragma unroll
        for (int m = 0; m < 4; m++)
#pragma unroll
            for (int n = 0; n < 4; n++)
                acc[m][n] = __builtin_amdgcn_mfma_f32_16x16x32_bf16(af[m], bfr[n], acc[m][n], 0, 0, 0);
        buf ^= 1;
    }

    const int cb = blockIdx.x * 128 + wc;
    const int rb_ = blockIdx.y * 128 + wr;
#pragma unroll
    for (int n = 0; n < 4; n++) {
        int col = cb + n * 16 + lr;
        float bv = bias[col];
#pragma unroll
        for (int m = 0; m < 4; m++) {
            int row0 = rb_ + m * 16 + lg * 4;
#pragma unroll
            for (int r = 0; r < 4; r++) {
                float v = acc[m][n][r] + bv;
                if (OUTF32) ((float*)Cv)[(long long)(row0 + r) * N + col] = v;
                else ((__bf16*)Cv)[(long long)(row0 + r) * N + col] = (__bf16)v;
            }
        }
    }
}

// ---------------- RMSNorm + RoPE, write [NH][SEQ][HD] ----------------
__global__ __launch_bounds__(256) void norm_rope(
    const __bf16* __restrict__ pre,   // [SEQ][DIM]
    const float* __restrict__ gvec,   // [DIM]
    const float* __restrict__ fcos,   // [1024][64]
    const float* __restrict__ fsin,
    __bf16* __restrict__ out) {       // [NH][SEQ][HD]
    const int s = blockIdx.x;
    const int t = threadIdx.x;
    float a[3], b[3];
    float ss = 0.f;
#pragma unroll
    for (int j = 0; j < 3; j++) {
        int p = t + 256 * j;
        bf16x2 v = *(const bf16x2*)(pre + (size_t)s * DIM + 2 * p);
        a[j] = (float)v[0]; b[j] = (float)v[1];
        ss += a[j] * a[j] + b[j] * b[j];
    }
    for (int off = 32; off; off >>= 1) ss += __shfl_down(ss, off);
    __shared__ float red[4];
    if ((t & 63) == 0) red[t >> 6] = ss;
    __syncthreads();
    float mean = (red[0] + red[1] + red[2] + red[3]) * (1.f / DIM);
    float rms = rsqrtf(mean + 1e-6f);
    const int fi = s / 640, hi2 = (s % 640) >> 5, wi = s & 31;
#pragma unroll
    for (int j = 0; j < 3; j++) {
        int p = t + 256 * j;
        int c = p & 63;
        int pos = (c < 22) ? fi : ((c < 43) ? hi2 : wi);
        float fc = fcos[pos * 64 + c];
        float fs = fsin[pos * 64 + c];
        float av = a[j] * rms * gvec[2 * p];
        float bv = b[j] * rms * gvec[2 * p + 1];
        float orr = av * fc - bv * fs;
        float oi = av * fs + bv * fc;
        int hh = p >> 6;
        bf16x2 o; o[0] = (__bf16)orr; o[1] = (__bf16)oi;
        *(bf16x2*)(out + ((size_t)hh * SEQ + s) * HD + 2 * c) = o;
    }
}

// ---------------- transpose [SEQ][DIM] -> [DIM][SEQ] with kv-slot permute ----
__global__ __launch_bounds__(256) void transpose_bf16(
    const __bf16* __restrict__ in, __bf16* __restrict__ out) {
    __shared__ __bf16 tile[64][68];
    const int t = threadIdx.x;
    const int sb = blockIdx.x * 64, cb = blockIdx.y * 64;
    const int tx = t & 15, ty = t >> 4;
#pragma unroll
    for (int i = 0; i < 4; i++) {
        int r = ty + i * 16;
        bf16x4 v = *(const bf16x4*)(in + (size_t)(sb + r) * DIM + cb + tx * 4);
        *(bf16x4*)&tile[r][tx * 4] = v;
    }
    __syncthreads();
    int s0 = sb + tx * 4;
    int j = (s0 >> 2) & 7;
    int u = (j < 4) ? (j << 1) : ((j << 1) - 7);
    int sp = (s0 & ~31) + (u << 2);
#pragma unroll
    for (int i = 0; i < 4; i++) {
        int c = ty + i * 16;
        bf16x4 v;
        v[0] = tile[tx * 4 + 0][c]; v[1] = tile[tx * 4 + 1][c];
        v[2] = tile[tx * 4 + 2][c]; v[3] = tile[tx * 4 + 3][c];
        *(bf16x4*)(out + (size_t)(cb + c) * SEQ + sp) = v;
    }
}

// ---------------- flash attention, LDS-shared K/V ----------------
// 240 blocks x 6 waves; each wave owns 32 q-rows (block: 192), all waves share
// double-buffered K[32][128]/V[128][32] LDS tiles staged via global_load_lds.
// K source pre-XOR-swizzled (byte ^= (row&7)<<4) so swizzled ds_reads are
// conflict-free; V tile layout is span-uniform already (linear).
// Fabric traffic /6 vs per-wave loads: 2.76 GB -> 0.46 GB per launch.
__global__ __launch_bounds__(384, 1) void attn(
    const __bf16* __restrict__ Q,    // [NH][SEQ][HD]
    const __bf16* __restrict__ Kk,   // [NH][SEQ][HD]
    const __bf16* __restrict__ Vp,   // [NH][HD][SEQ] (kv-permuted in 32-blocks)
    __bf16* __restrict__ O) {        // [SEQ][DIM]
    __shared__ __bf16 Ks[2][32 * 128];   // 8 KB per buffer
    __shared__ __bf16 Vs[2][128 * 32];   // 8 KB per buffer

    const int bid = blockIdx.x;
    const int task = (bid & 7) * 30 + (bid >> 3);   // XCD-bijective (240 = 8*30)
    const int h = task / 20;
    const int qb = task % 20;
    const int t = threadIdx.x;
    const int wv = t >> 6;
    const int lane = t & 63;
    const int lq = lane & 15, g = lane >> 4;
    const int q0 = qb * 192 + wv * 32;

    const __bf16* Qh = Q + (size_t)h * SEQ * HD;
    const __bf16* Kh = Kk + (size_t)h * SEQ * HD;
    const __bf16* Vh = Vp + (size_t)h * HD * SEQ;

    bf16x8 qf[2][4];
#pragma unroll
    for (int qg = 0; qg < 2; qg++)
#pragma unroll
        for (int c = 0; c < 4; c++)
            qf[qg][c] = *(const bf16x8*)(Qh + (size_t)(q0 + qg * 16 + lq) * HD + c * 32 + g * 8);

    f32x4 acc[8][2] = {};
    float m[2] = {-1e30f, -1e30f}, l[2] = {0.f, 0.f};
    const float SCL2 = 0.1275365308119098f;   // (1/sqrt(128)) * log2(e)
    const float THR_RAW = 90.50966799187809f; // 8 nats / (1/sqrt(128))

    // staging: 16 chunks of 1KB (8 K + 8 V) split over 6 waves
    const int krow = lane >> 4;            // + c*4 -> kv row
    const int kcb = (lane & 15) * 16;      // byte col within K row (pre-swizzle)
    const int vd = lane >> 2;              // + cc*16 -> d row
    const int vce = (lane & 3) * 8;        // elem col within V row
    auto stage = [&](int kv0, int b) {
        for (int c = wv; c < 16; c += 6) {
            if (c < 8) {
                int r = c * 4 + krow;
                int cb = kcb ^ ((r & 7) << 4);
                GLLD(Kh + (size_t)(kv0 + r) * HD + (cb >> 1), &Ks[b][c * 512]);
            } else {
                int cc = c - 8;
                GLLD(Vh + (size_t)(cc * 16 + vd) * SEQ + kv0 + vce, &Vs[b][cc * 512]);
            }
        }
    };

    stage(0, 0);
    int buf = 0;
#pragma unroll 1
    for (int i = 0; i < 120; i++) {
        __syncthreads();               // stage(i) drained; prev reads done before overwrite
        if (i + 1 < 120) stage((i + 1) * 32, buf ^ 1);   // flies under compute below
        const __bf16* Kb_ = &Ks[buf][0];
        const __bf16* Vb_ = &Vs[buf][0];

        // ---- QK^T (swapped: mfma(K, Q) -> scores col = q = lane&15) ----
        f32x4 sc[2][2] = {};
        const int kswz = (lq & 7) << 4;
        __builtin_amdgcn_s_setprio(1);
#pragma unroll
        for (int c = 0; c < 4; c++) {
            int cb = (c * 64 + g * 16) ^ kswz;
            bf16x8 k0 = *(const bf16x8*)(Kb_ + lq * 128 + (cb >> 1));
            bf16x8 k1 = *(const bf16x8*)(Kb_ + (16 + lq) * 128 + (cb >> 1));
            sc[0][0] = __builtin_amdgcn_mfma_f32_16x16x32_bf16(k0, qf[0][c], sc[0][0], 0, 0, 0);
            sc[0][1] = __builtin_amdgcn_mfma_f32_16x16x32_bf16(k0, qf[1][c], sc[0][1], 0, 0, 0);
            sc[1][0] = __builtin_amdgcn_mfma_f32_16x16x32_bf16(k1, qf[0][c], sc[1][0], 0, 0, 0);
            sc[1][1] = __builtin_amdgcn_mfma_f32_16x16x32_bf16(k1, qf[1][c], sc[1][1], 0, 0, 0);
        }
        __builtin_amdgcn_s_setprio(0);

        // ---- online softmax (per q = lane&15; reduce over g via shfl) ----
        bf16x8 pa[2];
#pragma unroll
        for (int qg = 0; qg < 2; qg++) {
            float pm = fmaxf(fmaxf(fmaxf(sc[0][qg][0], sc[0][qg][1]), fmaxf(sc[0][qg][2], sc[0][qg][3])),
                             fmaxf(fmaxf(sc[1][qg][0], sc[1][qg][1]), fmaxf(sc[1][qg][2], sc[1][qg][3])));
            pm = fmaxf(pm, __shfl_xor(pm, 16));
            pm = fmaxf(pm, __shfl_xor(pm, 32));
            if (!__all(pm <= m[qg] + THR_RAW)) {   // defer-max
                float mn = fmaxf(m[qg], pm);
                float al = __builtin_amdgcn_exp2f(SCL2 * (m[qg] - mn));
                m[qg] = mn;
                l[qg] *= al;
#pragma unroll
                for (int dt = 0; dt < 8; dt++)
#pragma unroll
                    for (int r = 0; r < 4; r++) acc[dt][qg][r] *= al;
            }
            float ms = SCL2 * m[qg];
            float p[8], ls = 0.f;
#pragma unroll
            for (int r = 0; r < 4; r++) { p[r] = __builtin_amdgcn_exp2f(SCL2 * sc[0][qg][r] - ms); ls += p[r]; }
#pragma unroll
            for (int r = 0; r < 4; r++) { p[4 + r] = __builtin_amdgcn_exp2f(SCL2 * sc[1][qg][r] - ms); ls += p[4 + r]; }
            ls += __shfl_xor(ls, 16);
            ls += __shfl_xor(ls, 32);
            l[qg] += ls;
#pragma unroll
            for (int i2 = 0; i2 < 8; i2++) pa[qg][i2] = (__bf16)p[i2];
        }

        // ---- PV (swapped: mfma(V^T, P^T); V kv-slots pre-permuted) ----
        bf16x8 vf[8];
#pragma unroll
        for (int dt = 0; dt < 8; dt++)
            vf[dt] = *(const bf16x8*)(Vb_ + (dt * 16 + lq) * 32 + g * 8);
        __builtin_amdgcn_s_setprio(1);
#pragma unroll
        for (int dt = 0; dt < 8; dt++) {
            acc[dt][0] = __builtin_amdgcn_mfma_f32_16x16x32_bf16(vf[dt], pa[0], acc[dt][0], 0, 0, 0);
            acc[dt][1] = __builtin_amdgcn_mfma_f32_16x16x32_bf16(vf[dt], pa[1], acc[dt][1], 0, 0, 0);
        }
        __builtin_amdgcn_s_setprio(0);
        buf ^= 1;
    }

#pragma unroll
    for (int qg = 0; qg < 2; qg++) {
        float inv = 1.f / l[qg];
#pragma unroll
        for (int dt = 0; dt < 8; dt++) {
            bf16x4 o;
#pragma unroll
            for (int r = 0; r < 4; r++) o[r] = (__bf16)(acc[dt][qg][r] * inv);
            *(bf16x4*)(O + (size_t)(q0 + qg * 16 + lq) * DIM + h * HD + dt * 16 + g * 4) = o;
        }
    }
}

extern "C" void kernel_launch(void* const* d_in, const int* in_sizes, int n_in,
                              void* d_out, int out_size, void* d_ws, size_t ws_size,
                              hipStream_t stream) {
    const float* x = (const float*)d_in[0];
    const float* Wq = (const float*)d_in[1];
    const float* bq = (const float*)d_in[2];
    const float* Wk = (const float*)d_in[3];
    const float* bk = (const float*)d_in[4];
    const float* Wv = (const float*)d_in[5];
    const float* bv = (const float*)d_in[6];
    const float* Wo = (const float*)d_in[7];
    const float* bo = (const float*)d_in[8];
    const float* gq = (const float*)d_in[9];
    const float* gk = (const float*)d_in[10];
    const float* fcos = (const float*)d_in[11];
    const float* fsin = (const float*)d_in[12];
    float* out = (float*)d_out;

    char* ws = (char*)d_ws;
    const size_t SZ_SD = (size_t)SEQ * DIM * 2;   // 11.25 MB
    const size_t SZ_W = (size_t)DIM * DIM * 2;    // 4.5 MB
    __bf16* xb   = (__bf16*)ws;            ws += SZ_SD;   // also reused as Qb
    __bf16* Wqb  = (__bf16*)ws;            ws += SZ_W;
    __bf16* Wkb  = (__bf16*)ws;            ws += SZ_W;
    __bf16* Wvb  = (__bf16*)ws;            ws += SZ_W;
    __bf16* Wob  = (__bf16*)ws;            ws += SZ_W;
    __bf16* qpre = (__bf16*)ws;            ws += SZ_SD;   // also reused as ob
    __bf16* kpre = (__bf16*)ws;            ws += SZ_SD;
    __bf16* vpre = (__bf16*)ws;            ws += SZ_SD;
    __bf16* Kb   = (__bf16*)ws;            ws += SZ_SD;
    __bf16* Vtb  = (__bf16*)ws;            ws += SZ_SD;
    __bf16* Qb = xb;     // xb dead after QKV GEMM
    __bf16* ob = qpre;   // qpre dead after norm_rope(q)

    int n4 = SEQ * DIM / 4;
    cvt_bf16<<<(n4 + 255) / 256, 256, 0, stream>>>(x, xb, n4);
    n4 = DIM * DIM / 4;
    cvt_bf16<<<(n4 + 255) / 256, 256, 0, stream>>>(Wq, Wqb, n4);
    cvt_bf16<<<(n4 + 255) / 256, 256, 0, stream>>>(Wk, Wkb, n4);
    cvt_bf16<<<(n4 + 255) / 256, 256, 0, stream>>>(Wv, Wvb, n4);
    cvt_bf16<<<(n4 + 255) / 256, 256, 0, stream>>>(Wo, Wob, n4);

    gemm_bt<0><<<dim3(DIM / 128, SEQ / 128, 3), 256, 0, stream>>>(
        xb, Wqb, Wkb, Wvb, bq, bk, bv, qpre, kpre, vpre, DIM, DIM);

    norm_rope<<<SEQ, 256, 0, stream>>>(qpre, gq, fcos, fsin, Qb);
    norm_rope<<<SEQ, 256, 0, stream>>>(kpre, gk, fcos, fsin, Kb);
    transpose_bf16<<<dim3(SEQ / 64, DIM / 64), 256, 0, stream>>>(vpre, Vtb);

    attn<<<dim3(240), 384, 0, stream>>>(Qb, Kb, Vtb, ob);

    gemm_bt<1><<<dim3(DIM / 128, SEQ / 128, 1), 256, 0, stream>>>(
        ob, Wob, Wob, Wob, bo, bo, bo, out, out, out, DIM, DIM);
}

// Round 5
// 320.809 us; speedup vs baseline: 1.5325x; 1.0473x over previous
//
#include <hip/hip_runtime.h>
#include <hip/hip_bf16.h>
#include <cstdint>

#define DIM 1536
#define NHEADS 12
#define HD 128
#define SEQ 3840

typedef float f32x4 __attribute__((ext_vector_type(4)));
typedef __bf16 bf16x8 __attribute__((ext_vector_type(8)));
typedef __bf16 bf16x4 __attribute__((ext_vector_type(4)));
typedef __bf16 bf16x2 __attribute__((ext_vector_type(2)));
typedef unsigned int u32;
typedef u32 u32x4 __attribute__((ext_vector_type(4)));

#define GLLD(g, l) __builtin_amdgcn_global_load_lds( \
    (const __attribute__((address_space(1))) void*)(g), \
    (__attribute__((address_space(3))) void*)(l), 16, 0, 0)

// ---------------- fp32 -> bf16 convert, 5 tensors in one launch ----------------
__global__ __launch_bounds__(256) void cvt_bf16_5(
    const float* __restrict__ s0, const float* __restrict__ s1, const float* __restrict__ s2,
    const float* __restrict__ s3, const float* __restrict__ s4,
    __bf16* __restrict__ d0, __bf16* __restrict__ d1, __bf16* __restrict__ d2,
    __bf16* __restrict__ d3, __bf16* __restrict__ d4,
    int n4_0, int n4_w) {
    const float* src; __bf16* dst; int n4;
    switch (blockIdx.y) {
        case 0: src = s0; dst = d0; n4 = n4_0; break;
        case 1: src = s1; dst = d1; n4 = n4_w; break;
        case 2: src = s2; dst = d2; n4 = n4_w; break;
        case 3: src = s3; dst = d3; n4 = n4_w; break;
        default: src = s4; dst = d4; n4 = n4_w; break;
    }
    int i = blockIdx.x * 256 + threadIdx.x;
    if (i < n4) {
        f32x4 v = ((const f32x4*)src)[i];
        bf16x4 o;
        o[0] = (__bf16)v[0]; o[1] = (__bf16)v[1];
        o[2] = (__bf16)v[2]; o[3] = (__bf16)v[3];
        ((bf16x4*)dst)[i] = o;
    }
}

// ---------------- GEMM: C[M][N] = A[M][K] * B[N][K]^T + bias ----------------
// 128x128 tile, BK=32, 4 waves (2x2); double-buffered global_load_lds staging.
template <int OUTF32>
__global__ __launch_bounds__(256) void gemm_bt(
    const __bf16* __restrict__ A,
    const __bf16* __restrict__ B0, const __bf16* __restrict__ B1, const __bf16* __restrict__ B2,
    const float* __restrict__ bias0, const float* __restrict__ bias1, const float* __restrict__ bias2,
    void* __restrict__ C0v, void* __restrict__ C1v, void* __restrict__ C2v,
    int N, int K) {
    const __bf16* B = B0; const float* bias = bias0; void* Cv = C0v;
    if (blockIdx.z == 1) { B = B1; bias = bias1; Cv = C1v; }
    else if (blockIdx.z == 2) { B = B2; bias = bias2; Cv = C2v; }

    __shared__ __bf16 As[2][128 * 32];
    __shared__ __bf16 Bs[2][128 * 32];

    const int t = threadIdx.x;
    const int w = t >> 6;
    const int lane = t & 63;
    const int lr = lane & 15, lg = lane >> 4;
    const int wr = (w >> 1) * 64, wc = (w & 1) * 64;
    const int wb = w * 512;

    const long long rowA = (long long)blockIdx.y * 128 + (t >> 2);
    const long long rowB = (long long)blockIdx.x * 128 + (t >> 2);
    const int kcol = (t & 3) * 8;

    const __bf16* pa0 = A + rowA * K + kcol;
    const __bf16* pa1 = pa0 + 64LL * K;
    const __bf16* pb0 = B + rowB * K + kcol;
    const __bf16* pb1 = pb0 + 64LL * K;

    f32x4 acc[4][4] = {};

    auto stage = [&](int kk, int b) {
        GLLD(pa0 + kk, &As[b][wb]);
        GLLD(pa1 + kk, &As[b][2048 + wb]);
        GLLD(pb0 + kk, &Bs[b][wb]);
        GLLD(pb1 + kk, &Bs[b][2048 + wb]);
    };

    stage(0, 0);
    int buf = 0;
#pragma unroll 1
    for (int kk = 0; kk < K; kk += 32) {
        __syncthreads();
        if (kk + 32 < K) stage(kk + 32, buf ^ 1);
        bf16x8 af[4], bfr[4];
#pragma unroll
        for (int m = 0; m < 4; m++)
            af[m] = *(const bf16x8*)(&As[buf][(wr + m * 16 + lr) * 32 + lg * 8]);
#pragma unroll
        for (int n = 0; n < 4; n++)
            bfr[n] = *(const bf16x8*)(&Bs[buf][(wc + n * 16 + lr) * 32 + lg * 8]);
#pragma unroll
        for (int m = 0; m < 4; m++)
#pragma unroll
            for (int n = 0; n < 4; n++)
                acc[m][n] = __builtin_amdgcn_mfma_f32_16x16x32_bf16(af[m], bfr[n], acc[m][n], 0, 0, 0);
        buf ^= 1;
    }

    const int cb = blockIdx.x * 128 + wc;
    const int rb_ = blockIdx.y * 128 + wr;
#pragma unroll
    for (int n = 0; n < 4; n++) {
        int col = cb + n * 16 + lr;
        float bv = bias[col];
#pragma unroll
        for (int m = 0; m < 4; m++) {
            int row0 = rb_ + m * 16 + lg * 4;
#pragma unroll
            for (int r = 0; r < 4; r++) {
                float v = acc[m][n][r] + bv;
                if (OUTF32) ((float*)Cv)[(long long)(row0 + r) * N + col] = v;
                else ((__bf16*)Cv)[(long long)(row0 + r) * N + col] = (__bf16)v;
            }
        }
    }
}

// ---------------- RMSNorm + RoPE, write [NH][SEQ][HD] ----------------
__global__ __launch_bounds__(256) void norm_rope(
    const __bf16* __restrict__ pre,   // [SEQ][DIM]
    const float* __restrict__ gvec,   // [DIM]
    const float* __restrict__ fcos,   // [1024][64]
    const float* __restrict__ fsin,
    __bf16* __restrict__ out) {       // [NH][SEQ][HD]
    const int s = blockIdx.x;
    const int t = threadIdx.x;
    float a[3], b[3];
    float ss = 0.f;
#pragma unroll
    for (int j = 0; j < 3; j++) {
        int p = t + 256 * j;
        bf16x2 v = *(const bf16x2*)(pre + (size_t)s * DIM + 2 * p);
        a[j] = (float)v[0]; b[j] = (float)v[1];
        ss += a[j] * a[j] + b[j] * b[j];
    }
    for (int off = 32; off; off >>= 1) ss += __shfl_down(ss, off);
    __shared__ float red[4];
    if ((t & 63) == 0) red[t >> 6] = ss;
    __syncthreads();
    float mean = (red[0] + red[1] + red[2] + red[3]) * (1.f / DIM);
    float rms = rsqrtf(mean + 1e-6f);
    const int fi = s / 640, hi2 = (s % 640) >> 5, wi = s & 31;
#pragma unroll
    for (int j = 0; j < 3; j++) {
        int p = t + 256 * j;
        int c = p & 63;
        int pos = (c < 22) ? fi : ((c < 43) ? hi2 : wi);
        float fc = fcos[pos * 64 + c];
        float fs = fsin[pos * 64 + c];
        float av = a[j] * rms * gvec[2 * p];
        float bv = b[j] * rms * gvec[2 * p + 1];
        float orr = av * fc - bv * fs;
        float oi = av * fs + bv * fc;
        int hh = p >> 6;
        bf16x2 o; o[0] = (__bf16)orr; o[1] = (__bf16)oi;
        *(bf16x2*)(out + ((size_t)hh * SEQ + s) * HD + 2 * c) = o;
    }
}

// ---------------- transpose [SEQ][DIM] -> [DIM][SEQ] with kv-slot permute ----
__global__ __launch_bounds__(256) void transpose_bf16(
    const __bf16* __restrict__ in, __bf16* __restrict__ out) {
    __shared__ __bf16 tile[64][68];
    const int t = threadIdx.x;
    const int sb = blockIdx.x * 64, cb = blockIdx.y * 64;
    const int tx = t & 15, ty = t >> 4;
#pragma unroll
    for (int i = 0; i < 4; i++) {
        int r = ty + i * 16;
        bf16x4 v = *(const bf16x4*)(in + (size_t)(sb + r) * DIM + cb + tx * 4);
        *(bf16x4*)&tile[r][tx * 4] = v;
    }
    __syncthreads();
    int s0 = sb + tx * 4;
    int j = (s0 >> 2) & 7;
    int u = (j < 4) ? (j << 1) : ((j << 1) - 7);
    int sp = (s0 & ~31) + (u << 2);
#pragma unroll
    for (int i = 0; i < 4; i++) {
        int c = ty + i * 16;
        bf16x4 v;
        v[0] = tile[tx * 4 + 0][c]; v[1] = tile[tx * 4 + 1][c];
        v[2] = tile[tx * 4 + 2][c]; v[3] = tile[tx * 4 + 3][c];
        *(bf16x4*)(out + (size_t)(cb + c) * SEQ + sp) = v;
    }
}

// ---------------- flash attention, LDS-shared K/V, KVBLK=64 ----------------
// 240 blocks x 6 waves; each wave owns 32 q-rows. Double-buffered K[64][128] /
// V[128][64] LDS tiles via global_load_lds; BOTH tiles XOR-swizzled
// (byte ^= (row&7)<<4) with pre-swizzled global source cols (both-sides rule),
// giving 2-way (free) ds_read_b128 bank patterns. Two 32-kv sub-steps per
// barrier -> half the barrier/vmcnt-drain stalls of KVBLK=32.
__global__ __launch_bounds__(384, 1) void attn(
    const __bf16* __restrict__ Q,    // [NH][SEQ][HD]
    const __bf16* __restrict__ Kk,   // [NH][SEQ][HD]
    const __bf16* __restrict__ Vp,   // [NH][HD][SEQ] (kv-permuted in 32-blocks)
    __bf16* __restrict__ O) {        // [SEQ][DIM]
    __shared__ __bf16 Ks[2][64 * 128];   // 16 KB per buffer
    __shared__ __bf16 Vs[2][128 * 64];   // 16 KB per buffer

    const int bid = blockIdx.x;
    const int task = (bid & 7) * 30 + (bid >> 3);   // XCD-bijective (240 = 8*30)
    const int h = task / 20;
    const int qb = task % 20;
    const int t = threadIdx.x;
    const int wv = t >> 6;
    const int lane = t & 63;
    const int lq = lane & 15, g = lane >> 4;
    const int q0 = qb * 192 + wv * 32;

    const __bf16* Qh = Q + (size_t)h * SEQ * HD;
    const __bf16* Kh = Kk + (size_t)h * SEQ * HD;
    const __bf16* Vh = Vp + (size_t)h * HD * SEQ;

    bf16x8 qf[2][4];
#pragma unroll
    for (int qg = 0; qg < 2; qg++)
#pragma unroll
        for (int c = 0; c < 4; c++)
            qf[qg][c] = *(const bf16x8*)(Qh + (size_t)(q0 + qg * 16 + lq) * HD + c * 32 + g * 8);

    f32x4 acc[8][2] = {};
    float m[2] = {-1e30f, -1e30f}, l[2] = {0.f, 0.f};
    const float SCL2 = 0.1275365308119098f;   // (1/sqrt(128)) * log2(e)
    const float THR_RAW = 90.50966799187809f; // 8 nats / (1/sqrt(128))

    // staging: 32 chunks of 1KB (16 K + 16 V) split over 6 waves.
    // K chunk c: rows c*4..+3 (256B each); V chunk cc: rows cc*8..+7 (128B each).
    // Global source col pre-XOR'd so LDS content is swizzled while GLLD dest
    // stays linear (lane*16B).
    const int krow_in = lane >> 4;                       // 0..3
    const int vrow_in = lane >> 3;                       // 0..7
    const int vce = (((lane & 7) ^ (lane >> 3))) * 8;    // V source col elems
    auto stage = [&](int kv0, int b) {
        for (int c = wv; c < 32; c += 6) {
            if (c < 16) {
                int r = c * 4 + krow_in;
                int cb = ((lane & 15) * 16) ^ ((r & 7) << 4);   // bytes
                GLLD(Kh + (size_t)(kv0 + r) * HD + (cb >> 1), &Ks[b][c * 512]);
            } else {
                int cc = c - 16;
                int rd = cc * 8 + vrow_in;
                GLLD(Vh + (size_t)rd * SEQ + kv0 + vce, &Vs[b][cc * 512]);
            }
        }
    };

    stage(0, 0);
    int buf = 0;
    const int kswz = (lq & 7) << 3;   // element-offset XOR for reads
#pragma unroll 1
    for (int i = 0; i < 60; i++) {
        __syncthreads();               // drains stage(i); prev buf reads done
        if (i + 1 < 60) stage((i + 1) * 64, buf ^ 1);   // flies under compute
        const __bf16* Kb_ = &Ks[buf][0];
        const __bf16* Vb_ = &Vs[buf][0];

#pragma unroll
        for (int s = 0; s < 2; s++) {
            // ---- QK^T (swapped: mfma(K, Q) -> score col = q = lane&15) ----
            f32x4 sc[2][2] = {};
            __builtin_amdgcn_s_setprio(1);
#pragma unroll
            for (int c = 0; c < 4; c++) {
                int cb = (c * 32 + g * 8) ^ kswz;
                bf16x8 k0 = *(const bf16x8*)(Kb_ + (s * 32 + lq) * 128 + cb);
                bf16x8 k1 = *(const bf16x8*)(Kb_ + (s * 32 + 16 + lq) * 128 + cb);
                sc[0][0] = __builtin_amdgcn_mfma_f32_16x16x32_bf16(k0, qf[0][c], sc[0][0], 0, 0, 0);
                sc[0][1] = __builtin_amdgcn_mfma_f32_16x16x32_bf16(k0, qf[1][c], sc[0][1], 0, 0, 0);
                sc[1][0] = __builtin_amdgcn_mfma_f32_16x16x32_bf16(k1, qf[0][c], sc[1][0], 0, 0, 0);
                sc[1][1] = __builtin_amdgcn_mfma_f32_16x16x32_bf16(k1, qf[1][c], sc[1][1], 0, 0, 0);
            }
            __builtin_amdgcn_s_setprio(0);

            // ---- online softmax (per q = lane&15; reduce over g via shfl) ----
            bf16x8 pa[2];
#pragma unroll
            for (int qg = 0; qg < 2; qg++) {
                float pm = fmaxf(fmaxf(fmaxf(sc[0][qg][0], sc[0][qg][1]), fmaxf(sc[0][qg][2], sc[0][qg][3])),
                                 fmaxf(fmaxf(sc[1][qg][0], sc[1][qg][1]), fmaxf(sc[1][qg][2], sc[1][qg][3])));
                pm = fmaxf(pm, __shfl_xor(pm, 16));
                pm = fmaxf(pm, __shfl_xor(pm, 32));
                if (!__all(pm <= m[qg] + THR_RAW)) {   // defer-max
                    float mn = fmaxf(m[qg], pm);
                    float al = __builtin_amdgcn_exp2f(SCL2 * (m[qg] - mn));
                    m[qg] = mn;
                    l[qg] *= al;
#pragma unroll
                    for (int dt = 0; dt < 8; dt++)
#pragma unroll
                        for (int r = 0; r < 4; r++) acc[dt][qg][r] *= al;
                }
                float ms = SCL2 * m[qg];
                float p[8], ls = 0.f;
#pragma unroll
                for (int r = 0; r < 4; r++) { p[r] = __builtin_amdgcn_exp2f(SCL2 * sc[0][qg][r] - ms); ls += p[r]; }
#pragma unroll
                for (int r = 0; r < 4; r++) { p[4 + r] = __builtin_amdgcn_exp2f(SCL2 * sc[1][qg][r] - ms); ls += p[4 + r]; }
                ls += __shfl_xor(ls, 16);
                ls += __shfl_xor(ls, 32);
                l[qg] += ls;
#pragma unroll
                for (int i2 = 0; i2 < 8; i2++) pa[qg][i2] = (__bf16)p[i2];
            }

            // ---- PV (swapped: mfma(V^T, P^T); V kv-slots pre-permuted) ----
            bf16x8 vf[8];
#pragma unroll
            for (int dt = 0; dt < 8; dt++)
                vf[dt] = *(const bf16x8*)(Vb_ + (dt * 16 + lq) * 64 + ((s * 32 + g * 8) ^ kswz));
            __builtin_amdgcn_s_setprio(1);
#pragma unroll
            for (int dt = 0; dt < 8; dt++) {
                acc[dt][0] = __builtin_amdgcn_mfma_f32_16x16x32_bf16(vf[dt], pa[0], acc[dt][0], 0, 0, 0);
                acc[dt][1] = __builtin_amdgcn_mfma_f32_16x16x32_bf16(vf[dt], pa[1], acc[dt][1], 0, 0, 0);
            }
            __builtin_amdgcn_s_setprio(0);
        }
        buf ^= 1;
    }

#pragma unroll
    for (int qg = 0; qg < 2; qg++) {
        float inv = 1.f / l[qg];
#pragma unroll
        for (int dt = 0; dt < 8; dt++) {
            bf16x4 o;
#pragma unroll
            for (int r = 0; r < 4; r++) o[r] = (__bf16)(acc[dt][qg][r] * inv);
            *(bf16x4*)(O + (size_t)(q0 + qg * 16 + lq) * DIM + h * HD + dt * 16 + g * 4) = o;
        }
    }
}

extern "C" void kernel_launch(void* const* d_in, const int* in_sizes, int n_in,
                              void* d_out, int out_size, void* d_ws, size_t ws_size,
                              hipStream_t stream) {
    const float* x = (const float*)d_in[0];
    const float* Wq = (const float*)d_in[1];
    const float* bq = (const float*)d_in[2];
    const float* Wk = (const float*)d_in[3];
    const float* bk = (const float*)d_in[4];
    const float* Wv = (const float*)d_in[5];
    const float* bv = (const float*)d_in[6];
    const float* Wo = (const float*)d_in[7];
    const float* bo = (const float*)d_in[8];
    const float* gq = (const float*)d_in[9];
    const float* gk = (const float*)d_in[10];
    const float* fcos = (const float*)d_in[11];
    const float* fsin = (const float*)d_in[12];
    float* out = (float*)d_out;

    char* ws = (char*)d_ws;
    const size_t SZ_SD = (size_t)SEQ * DIM * 2;   // 11.25 MB
    const size_t SZ_W = (size_t)DIM * DIM * 2;    // 4.5 MB
    __bf16* xb   = (__bf16*)ws;            ws += SZ_SD;   // also reused as Qb
    __bf16* Wqb  = (__bf16*)ws;            ws += SZ_W;
    __bf16* Wkb  = (__bf16*)ws;            ws += SZ_W;
    __bf16* Wvb  = (__bf16*)ws;            ws += SZ_W;
    __bf16* Wob  = (__bf16*)ws;            ws += SZ_W;
    __bf16* qpre = (__bf16*)ws;            ws += SZ_SD;   // also reused as ob
    __bf16* kpre = (__bf16*)ws;            ws += SZ_SD;
    __bf16* vpre = (__bf16*)ws;            ws += SZ_SD;
    __bf16* Kb   = (__bf16*)ws;            ws += SZ_SD;
    __bf16* Vtb  = (__bf16*)ws;            ws += SZ_SD;
    __bf16* Qb = xb;     // xb dead after QKV GEMM
    __bf16* ob = qpre;   // qpre dead after norm_rope(q)

    const int n4_x = SEQ * DIM / 4;
    const int n4_w = DIM * DIM / 4;
    cvt_bf16_5<<<dim3((n4_x + 255) / 256, 5), 256, 0, stream>>>(
        x, Wq, Wk, Wv, Wo, xb, Wqb, Wkb, Wvb, Wob, n4_x, n4_w);

    gemm_bt<0><<<dim3(DIM / 128, SEQ / 128, 3), 256, 0, stream>>>(
        xb, Wqb, Wkb, Wvb, bq, bk, bv, qpre, kpre, vpre, DIM, DIM);

    norm_rope<<<SEQ, 256, 0, stream>>>(qpre, gq, fcos, fsin, Qb);
    norm_rope<<<SEQ, 256, 0, stream>>>(kpre, gk, fcos, fsin, Kb);
    transpose_bf16<<<dim3(SEQ / 64, DIM / 64), 256, 0, stream>>>(vpre, Vtb);

    attn<<<dim3(240), 384, 0, stream>>>(Qb, Kb, Vtb, ob);

    gemm_bt<1><<<dim3(DIM / 128, SEQ / 128, 1), 256, 0, stream>>>(
        ob, Wob, Wob, Wob, bo, bo, bo, out, out, out, DIM, DIM);
}